// Round 1
// baseline (538.904 us; speedup 1.0000x reference)
//
#include <hip/hip_runtime.h>
#include <hip/hip_bf16.h>

#define B_  32
#define C1  1024
#define C2  256
#define T_  2048
#define EPSF 1e-5f
#define ROWP 40   // padded LDS row length in halfwords: 80 B, multiple of 16 B

typedef __attribute__((ext_vector_type(8))) short bf16x8;
typedef __attribute__((ext_vector_type(4))) float f32x4;

static __device__ __forceinline__ unsigned short f2bf(float f) {
    union { float f; unsigned u; } v; v.f = f;
    unsigned r = v.u + 0x7fffu + ((v.u >> 16) & 1u);   // RNE
    return (unsigned short)(r >> 16);
}
static __device__ __forceinline__ float bf2f(unsigned short h) {
    union { unsigned u; float f; } v; v.u = ((unsigned)h) << 16;
    return v.f;
}

// ---------------- K1: per-channel stats of x -> scale1/shift1 ----------------
__global__ void k_stats1(const float* __restrict__ x,
                         const float* __restrict__ g1, const float* __restrict__ bb1,
                         float* __restrict__ scale1, float* __restrict__ shift1) {
    int c = blockIdx.x, tid = threadIdx.x;
    float s = 0.f, sq = 0.f;
    for (int b = 0; b < B_; ++b) {
        const float4* row = (const float4*)(x + (size_t)b * C1 * T_ + (size_t)c * T_);
        for (int i = tid; i < T_ / 4; i += 256) {
            float4 v = row[i];
            s  += v.x + v.y + v.z + v.w;
            sq += v.x * v.x + v.y * v.y + v.z * v.z + v.w * v.w;
        }
    }
    __shared__ float rs[256], rq[256];
    rs[tid] = s; rq[tid] = sq; __syncthreads();
    for (int off = 128; off > 0; off >>= 1) {
        if (tid < off) { rs[tid] += rs[tid + off]; rq[tid] += rq[tid + off]; }
        __syncthreads();
    }
    if (tid == 0) {
        float n = (float)(B_ * T_);
        float mean = rs[0] / n;
        float var  = rq[0] / n - mean * mean;
        float sc   = g1[c] * rsqrtf(var + EPSF);
        scale1[c] = sc;
        shift1[c] = bb1[c] - mean * sc;
    }
}

// ---------------- K2: fold BN1 into w1 -> w1_eff (bf16), b1_eff --------------
__global__ void k_fold1(const float* __restrict__ w1, const float* __restrict__ b1,
                        const float* __restrict__ scale1, const float* __restrict__ shift1,
                        unsigned short* __restrict__ w1e, float* __restrict__ b1e) {
    int o = blockIdx.x, tid = threadIdx.x;
    float4 w = ((const float4*)(w1 + (size_t)o * C1))[tid];
    int c = tid * 4;
    float p = w.x * shift1[c] + w.y * shift1[c + 1] + w.z * shift1[c + 2] + w.w * shift1[c + 3];
    uint2 pk;
    pk.x = (unsigned)f2bf(w.x * scale1[c])     | ((unsigned)f2bf(w.y * scale1[c + 1]) << 16);
    pk.y = (unsigned)f2bf(w.z * scale1[c + 2]) | ((unsigned)f2bf(w.w * scale1[c + 3]) << 16);
    *((uint2*)(w1e + (size_t)o * C1 + c)) = pk;
    __shared__ float rs[256];
    rs[tid] = p; __syncthreads();
    for (int off = 128; off > 0; off >>= 1) {
        if (tid < off) rs[tid] += rs[tid + off];
        __syncthreads();
    }
    if (tid == 0) b1e[o] = b1[o] + rs[0];
}

// ---------------- K3: GEMM1: h = relu(w1_eff @ x + b1_eff), bf16 out --------
// Block tile 128(o) x 128(t), BK=32, per-batch. 4 waves in 2x2, each 64x64.
__global__ __launch_bounds__(256) void k_gemm1(const float* __restrict__ x,
        const unsigned short* __restrict__ w1e, const float* __restrict__ b1e,
        unsigned short* __restrict__ h) {
    __shared__ unsigned short sA[128 * ROWP];   // [m][k], rows padded to 40
    __shared__ unsigned short sB[128 * ROWP];   // [n=t][k], transposed at staging
    int bm = blockIdx.x, bn = blockIdx.y, b = blockIdx.z;
    int tid = threadIdx.x;
    int wave = tid >> 6, lane = tid & 63;
    int wm = wave >> 1, wn = wave & 1;
    int l15 = lane & 15, q = lane >> 4;
    f32x4 acc[4][4] = {};
    const size_t xbase = (size_t)b * C1 * T_ + (size_t)bn * 128;

    for (int k0 = 0; k0 < C1; k0 += 32) {
        // stage A: 128 rows x 32 bf16 from w1_eff (k-contiguous)
        #pragma unroll
        for (int i = 0; i < 2; ++i) {
            int chunk = tid + i * 256;            // 512 chunks of 8 bf16
            int row = chunk >> 2, cq = chunk & 3;
            uint4 v = *((const uint4*)(w1e + (size_t)(bm * 128 + row) * C1 + k0 + cq * 8));
            *((uint4*)&sA[row * ROWP + cq * 8]) = v;
        }
        // stage B: transpose 32(k) x 128(t) fp32 tile of x into [t][k] bf16
        #pragma unroll
        for (int i = 0; i < 2; ++i) {
            int task = tid + i * 256;             // 512 tasks: (k-pair, t-quad)
            int kp = task >> 5, tq = task & 31;
            const float* p0 = x + xbase + (size_t)(k0 + 2 * kp) * T_ + tq * 4;
            float4 r0 = *((const float4*)p0);
            float4 r1 = *((const float4*)(p0 + T_));
            int tl = tq * 4;
            *((unsigned*)&sB[(tl + 0) * ROWP + 2 * kp]) = (unsigned)f2bf(r0.x) | ((unsigned)f2bf(r1.x) << 16);
            *((unsigned*)&sB[(tl + 1) * ROWP + 2 * kp]) = (unsigned)f2bf(r0.y) | ((unsigned)f2bf(r1.y) << 16);
            *((unsigned*)&sB[(tl + 2) * ROWP + 2 * kp]) = (unsigned)f2bf(r0.z) | ((unsigned)f2bf(r1.z) << 16);
            *((unsigned*)&sB[(tl + 3) * ROWP + 2 * kp]) = (unsigned)f2bf(r0.w) | ((unsigned)f2bf(r1.w) << 16);
        }
        __syncthreads();
        bf16x8 af[4], bfr[4];
        #pragma unroll
        for (int mi = 0; mi < 4; ++mi)
            af[mi] = *((const bf16x8*)&sA[(wm * 64 + mi * 16 + l15) * ROWP + q * 8]);
        #pragma unroll
        for (int ni = 0; ni < 4; ++ni)
            bfr[ni] = *((const bf16x8*)&sB[(wn * 64 + ni * 16 + l15) * ROWP + q * 8]);
        #pragma unroll
        for (int mi = 0; mi < 4; ++mi)
            #pragma unroll
            for (int ni = 0; ni < 4; ++ni)
                acc[mi][ni] = __builtin_amdgcn_mfma_f32_16x16x32_bf16(af[mi], bfr[ni], acc[mi][ni], 0, 0, 0);
        __syncthreads();
    }
    // epilogue: bias + relu -> h bf16.  C/D layout: col=lane&15, row=q*4+reg
    int obase = bm * 128 + wm * 64;
    int tbase = bn * 128 + wn * 64;
    #pragma unroll
    for (int mi = 0; mi < 4; ++mi) {
        #pragma unroll
        for (int reg = 0; reg < 4; ++reg) {
            int o = obase + mi * 16 + q * 4 + reg;
            float bias = b1e[o];
            size_t hb = (size_t)b * C2 * T_ + (size_t)o * T_ + tbase;
            #pragma unroll
            for (int ni = 0; ni < 4; ++ni) {
                float v = acc[mi][ni][reg] + bias;
                v = v > 0.f ? v : 0.f;
                h[hb + ni * 16 + l15] = f2bf(v);
            }
        }
    }
}

// ---------------- K4: per-channel stats of h -> scale2/shift2 ----------------
__global__ void k_stats2(const unsigned short* __restrict__ h,
                         const float* __restrict__ g2, const float* __restrict__ bb2,
                         float* __restrict__ scale2, float* __restrict__ shift2) {
    int c = blockIdx.x, tid = threadIdx.x;
    float s = 0.f, sq = 0.f;
    for (int b = 0; b < B_; ++b) {
        const ushort4* row = (const ushort4*)(h + (size_t)b * C2 * T_ + (size_t)c * T_);
        for (int i = tid; i < T_ / 4; i += 256) {
            ushort4 v = row[i];
            float a0 = bf2f(v.x), a1 = bf2f(v.y), a2 = bf2f(v.z), a3 = bf2f(v.w);
            s  += a0 + a1 + a2 + a3;
            sq += a0 * a0 + a1 * a1 + a2 * a2 + a3 * a3;
        }
    }
    __shared__ float rs[256], rq[256];
    rs[tid] = s; rq[tid] = sq; __syncthreads();
    for (int off = 128; off > 0; off >>= 1) {
        if (tid < off) { rs[tid] += rs[tid + off]; rq[tid] += rq[tid + off]; }
        __syncthreads();
    }
    if (tid == 0) {
        float n = (float)(B_ * T_);
        float mean = rs[0] / n;
        float var  = rq[0] / n - mean * mean;
        float sc   = g2[c] * rsqrtf(var + EPSF);
        scale2[c] = sc;
        shift2[c] = bb2[c] - mean * sc;
    }
}

// ---------------- K5: fold BN2 into w2 -> w2_eff (bf16), b2_eff --------------
__global__ void k_fold2(const float* __restrict__ w2, const float* __restrict__ b2,
                        const float* __restrict__ scale2, const float* __restrict__ shift2,
                        unsigned short* __restrict__ w2e, float* __restrict__ b2e) {
    int o = blockIdx.x, tid = threadIdx.x;   // 64 blocks x 256 threads (tid == c2)
    float w = w2[(size_t)o * C2 + tid];
    float p = w * shift2[tid];
    w2e[(size_t)o * C2 + tid] = f2bf(w * scale2[tid]);
    __shared__ float rs[256];
    rs[tid] = p; __syncthreads();
    for (int off = 128; off > 0; off >>= 1) {
        if (tid < off) rs[tid] += rs[tid + off];
        __syncthreads();
    }
    if (tid == 0) b2e[o] = b2[o] + rs[0];
}

// ---------------- K6: GEMM2: out = w2_eff @ h + b2_eff, split mu/logvar -----
// Block tile 64(o) x 128(t), BK=32, K=256. 4 waves side-by-side in t, each 64x32.
__global__ __launch_bounds__(256) void k_gemm2(const unsigned short* __restrict__ h,
        const unsigned short* __restrict__ w2e, const float* __restrict__ b2e,
        float* __restrict__ out) {
    __shared__ unsigned short sA[64 * ROWP];
    __shared__ unsigned short sB[128 * ROWP];
    int bn = blockIdx.x, b = blockIdx.y;
    int tid = threadIdx.x;
    int wave = tid >> 6, lane = tid & 63;
    int l15 = lane & 15, q = lane >> 4;
    f32x4 acc[4][2] = {};
    const size_t hbase = (size_t)b * C2 * T_ + (size_t)bn * 128;

    for (int k0 = 0; k0 < C2; k0 += 32) {
        // stage A: 64 rows x 32 bf16 of w2_eff (one 16B chunk per thread)
        {
            int row = tid >> 2, cq = tid & 3;
            uint4 v = *((const uint4*)(w2e + (size_t)row * C2 + k0 + cq * 8));
            *((uint4*)&sA[row * ROWP + cq * 8]) = v;
        }
        // stage B: transpose 32(k) x 128(t) bf16 tile of h into [t][k]
        #pragma unroll
        for (int i = 0; i < 2; ++i) {
            int task = tid + i * 256;
            int kp = task >> 5, tq = task & 31;
            const unsigned short* p0 = h + hbase + (size_t)(k0 + 2 * kp) * T_ + tq * 4;
            uint2 r0 = *((const uint2*)p0);
            uint2 r1 = *((const uint2*)(p0 + T_));
            unsigned a0 = r0.x & 0xffffu, a1 = r0.x >> 16, a2 = r0.y & 0xffffu, a3 = r0.y >> 16;
            unsigned c0 = r1.x & 0xffffu, c1 = r1.x >> 16, c2 = r1.y & 0xffffu, c3 = r1.y >> 16;
            int tl = tq * 4;
            *((unsigned*)&sB[(tl + 0) * ROWP + 2 * kp]) = a0 | (c0 << 16);
            *((unsigned*)&sB[(tl + 1) * ROWP + 2 * kp]) = a1 | (c1 << 16);
            *((unsigned*)&sB[(tl + 2) * ROWP + 2 * kp]) = a2 | (c2 << 16);
            *((unsigned*)&sB[(tl + 3) * ROWP + 2 * kp]) = a3 | (c3 << 16);
        }
        __syncthreads();
        bf16x8 af[4], bfr[2];
        #pragma unroll
        for (int mi = 0; mi < 4; ++mi)
            af[mi] = *((const bf16x8*)&sA[(mi * 16 + l15) * ROWP + q * 8]);
        #pragma unroll
        for (int ni = 0; ni < 2; ++ni)
            bfr[ni] = *((const bf16x8*)&sB[(wave * 32 + ni * 16 + l15) * ROWP + q * 8]);
        #pragma unroll
        for (int mi = 0; mi < 4; ++mi)
            #pragma unroll
            for (int ni = 0; ni < 2; ++ni)
                acc[mi][ni] = __builtin_amdgcn_mfma_f32_16x16x32_bf16(af[mi], bfr[ni], acc[mi][ni], 0, 0, 0);
        __syncthreads();
    }
    // epilogue: + bias, split into mu (o<32) / logvar (o>=32), fp32 out
    int tbase = bn * 128 + wave * 32;
    #pragma unroll
    for (int mi = 0; mi < 4; ++mi) {
        #pragma unroll
        for (int reg = 0; reg < 4; ++reg) {
            int o = mi * 16 + q * 4 + reg;
            float bias = b2e[o];
            size_t base = (o < 32)
                ? ((size_t)b * 32 * T_ + (size_t)o * T_)
                : (2097152u + (size_t)b * 32 * T_ + (size_t)(o - 32) * T_);
            #pragma unroll
            for (int ni = 0; ni < 2; ++ni) {
                int t = tbase + ni * 16 + l15;
                out[base + t] = acc[mi][ni][reg] + bias;
            }
        }
    }
}

extern "C" void kernel_launch(void* const* d_in, const int* in_sizes, int n_in,
                              void* d_out, int out_size, void* d_ws, size_t ws_size,
                              hipStream_t stream) {
    const float* x   = (const float*)d_in[0];
    const float* g1  = (const float*)d_in[1];
    const float* bb1 = (const float*)d_in[2];
    const float* w1  = (const float*)d_in[3];
    const float* b1  = (const float*)d_in[4];
    const float* g2  = (const float*)d_in[5];
    const float* bb2 = (const float*)d_in[6];
    const float* w2  = (const float*)d_in[7];
    const float* b2  = (const float*)d_in[8];
    float* out = (float*)d_out;

    char* ws = (char*)d_ws;
    float* scale1 = (float*)(ws + 0);
    float* shift1 = (float*)(ws + 4096);
    float* b1e    = (float*)(ws + 8192);
    float* scale2 = (float*)(ws + 9216);
    float* shift2 = (float*)(ws + 10240);
    float* b2e    = (float*)(ws + 11264);
    unsigned short* w1e = (unsigned short*)(ws + 12288);            // 512 KiB
    unsigned short* w2e = (unsigned short*)(ws + 12288 + 524288);   // 32 KiB
    unsigned short* h   = (unsigned short*)(ws + 573440);           // 32 MiB

    k_stats1<<<dim3(1024), dim3(256), 0, stream>>>(x, g1, bb1, scale1, shift1);
    k_fold1 <<<dim3(256),  dim3(256), 0, stream>>>(w1, b1, scale1, shift1, w1e, b1e);
    k_gemm1 <<<dim3(2, 16, 32), dim3(256), 0, stream>>>(x, w1e, b1e, h);
    k_stats2<<<dim3(256),  dim3(256), 0, stream>>>(h, g2, bb2, scale2, shift2);
    k_fold2 <<<dim3(64),   dim3(256), 0, stream>>>(w2, b2, scale2, shift2, w2e, b2e);
    k_gemm2 <<<dim3(16, 32), dim3(256), 0, stream>>>(h, w2e, b2e, out);
}

// Round 2
// 538.136 us; speedup vs baseline: 1.0014x; 1.0014x over previous
//
#include <hip/hip_runtime.h>

#define B_  32
#define C1  1024
#define C2  256
#define T_  2048
#define EPSF 1e-5f
#define CPAD 72   // prep LDS row pitch in halfwords (144 B: 16-B aligned rows)

typedef __attribute__((ext_vector_type(8))) short bf16x8;
typedef __attribute__((ext_vector_type(4))) float f32x4;

static __device__ __forceinline__ unsigned short f2bf(float f) {
    union { float f; unsigned u; } v; v.f = f;
    unsigned r = v.u + 0x7fffu + ((v.u >> 16) & 1u);   // RNE
    return (unsigned short)(r >> 16);
}
static __device__ __forceinline__ float bf2f(unsigned short h) {
    union { unsigned u; float f; } v; v.u = ((unsigned)h) << 16;
    return v.f;
}
// async global->LDS, 16 B per lane; lds dest = wave-uniform base + lane*16
static __device__ __forceinline__ void g2l16(const void* g, void* l) {
    __builtin_amdgcn_global_load_lds(
        (const __attribute__((address_space(1))) unsigned int*)g,
        (__attribute__((address_space(3))) unsigned int*)l, 16, 0, 0);
}

// ---- K1: fused transpose+convert+partial stats: x[b][c][t] -> xT[b][t][c] bf16
__global__ __launch_bounds__(256) void k_prep(const float* __restrict__ x,
        unsigned short* __restrict__ xT, float* __restrict__ psum, float* __restrict__ psq) {
    __shared__ unsigned short tile[64 * CPAD];
    __shared__ float red[256];
    int ct = blockIdx.x, b = blockIdx.y, tid = threadIdx.x;
    int c0 = ct * 64;
    int cl = tid >> 2, t4 = tid & 3;
    const float* xrow = x + (size_t)b * C1 * T_ + (size_t)(c0 + cl) * T_;
    float s = 0.f, sq = 0.f;
    for (int t0 = 0; t0 < T_; t0 += 64) {
        #pragma unroll
        for (int j = 0; j < 4; ++j) {
            int tl = j * 16 + t4 * 4;
            float4 v = *(const float4*)(xrow + t0 + tl);
            s  += v.x + v.y + v.z + v.w;
            sq += v.x * v.x + v.y * v.y + v.z * v.z + v.w * v.w;
            tile[(tl + 0) * CPAD + cl] = f2bf(v.x);
            tile[(tl + 1) * CPAD + cl] = f2bf(v.y);
            tile[(tl + 2) * CPAD + cl] = f2bf(v.z);
            tile[(tl + 3) * CPAD + cl] = f2bf(v.w);
        }
        __syncthreads();
        #pragma unroll
        for (int j = 0; j < 2; ++j) {
            int w = tid + j * 256;
            int tl = w >> 3, cu = w & 7;
            uint4 vv = *(const uint4*)&tile[tl * CPAD + cu * 8];
            *(uint4*)&xT[((size_t)b * T_ + t0 + tl) * C1 + c0 + cu * 8] = vv;
        }
        __syncthreads();
    }
    red[tid] = s; __syncthreads();
    if (tid < 64)
        psum[(size_t)b * C1 + c0 + tid] = red[4*tid] + red[4*tid+1] + red[4*tid+2] + red[4*tid+3];
    __syncthreads();
    red[tid] = sq; __syncthreads();
    if (tid < 64)
        psq[(size_t)b * C1 + c0 + tid]  = red[4*tid] + red[4*tid+1] + red[4*tid+2] + red[4*tid+3];
}

// ---- K2: reduce partials -> scale1/shift1 (grid 4 x 256)
__global__ void k_scales1(const float* __restrict__ psum, const float* __restrict__ psq,
        const float* __restrict__ g, const float* __restrict__ bb,
        float* __restrict__ scale, float* __restrict__ shift) {
    int c = blockIdx.x * 256 + threadIdx.x;
    float s = 0.f, sq = 0.f;
    for (int b = 0; b < B_; ++b) { s += psum[b * C1 + c]; sq += psq[b * C1 + c]; }
    float n = (float)(B_ * T_);
    float mean = s / n;
    float var  = sq / n - mean * mean;
    float sc   = g[c] * rsqrtf(var + EPSF);
    scale[c] = sc;
    shift[c] = bb[c] - mean * sc;
}

// ---- K3: fold BN1 into w1 -> w1e bf16, b1e
__global__ void k_fold1(const float* __restrict__ w1, const float* __restrict__ b1,
                        const float* __restrict__ scale1, const float* __restrict__ shift1,
                        unsigned short* __restrict__ w1e, float* __restrict__ b1e) {
    int o = blockIdx.x, tid = threadIdx.x;
    float4 w = ((const float4*)(w1 + (size_t)o * C1))[tid];
    int c = tid * 4;
    float p = w.x * shift1[c] + w.y * shift1[c + 1] + w.z * shift1[c + 2] + w.w * shift1[c + 3];
    uint2 pk;
    pk.x = (unsigned)f2bf(w.x * scale1[c])     | ((unsigned)f2bf(w.y * scale1[c + 1]) << 16);
    pk.y = (unsigned)f2bf(w.z * scale1[c + 2]) | ((unsigned)f2bf(w.w * scale1[c + 3]) << 16);
    *((uint2*)(w1e + (size_t)o * C1 + c)) = pk;
    __shared__ float rs[256];
    rs[tid] = p; __syncthreads();
    for (int off = 128; off > 0; off >>= 1) {
        if (tid < off) rs[tid] += rs[tid + off];
        __syncthreads();
    }
    if (tid == 0) b1e[o] = b1[o] + rs[0];
}

// ---- K4: GEMM1: hT[b][t][o] = relu(w1e @ xT + b1e), bf16.
// 128(o) x 128(t) tile, BK=32, async global_load_lds staging, unpadded LDS rows.
__global__ __launch_bounds__(256) void k_gemm1(const unsigned short* __restrict__ xT,
        const unsigned short* __restrict__ w1e, const float* __restrict__ b1e,
        unsigned short* __restrict__ hT) {
    __shared__ unsigned short sA[128 * 32];
    __shared__ unsigned short sB[128 * 32];
    int bm = blockIdx.x, bn = blockIdx.y, b = blockIdx.z;
    int tid = threadIdx.x;
    int wave = tid >> 6, lane = tid & 63;
    int wm = wave >> 1, wn = wave & 1;
    int l15 = lane & 15, q = lane >> 4;
    f32x4 acc[4][4] = {};
    const unsigned short* xblk = xT + ((size_t)b * T_ + (size_t)bn * 128) * C1;
    const unsigned short* wblk = w1e + (size_t)(bm * 128) * C1;

    for (int k0 = 0; k0 < C1; k0 += 32) {
        #pragma unroll
        for (int i = 0; i < 2; ++i) {
            int idx = (wave * 2 + i) * 64 + lane;     // 0..511
            int row = idx >> 2, cq = idx & 3;
            g2l16(wblk + (size_t)row * C1 + k0 + cq * 8, &sA[(wave * 2 + i) * 512]);
            g2l16(xblk + (size_t)row * C1 + k0 + cq * 8, &sB[(wave * 2 + i) * 512]);
        }
        __syncthreads();
        bf16x8 af[4], bfr[4];
        #pragma unroll
        for (int mi = 0; mi < 4; ++mi)
            af[mi] = *((const bf16x8*)&sA[(wm * 64 + mi * 16 + l15) * 32 + q * 8]);
        #pragma unroll
        for (int ni = 0; ni < 4; ++ni)
            bfr[ni] = *((const bf16x8*)&sB[(wn * 64 + ni * 16 + l15) * 32 + q * 8]);
        #pragma unroll
        for (int mi = 0; mi < 4; ++mi)
            #pragma unroll
            for (int ni = 0; ni < 4; ++ni)
                acc[mi][ni] = __builtin_amdgcn_mfma_f32_16x16x32_bf16(af[mi], bfr[ni], acc[mi][ni], 0, 0, 0);
        __syncthreads();
    }
    // epilogue: C/D layout col(t)=l15, row(o)=q*4+reg -> 4 consecutive o per lane
    int obase = bm * 128 + wm * 64;
    int tbase = bn * 128 + wn * 64;
    #pragma unroll
    for (int mi = 0; mi < 4; ++mi) {
        float4 bias = *(const float4*)&b1e[obase + mi * 16 + q * 4];
        #pragma unroll
        for (int ni = 0; ni < 4; ++ni) {
            int t = tbase + ni * 16 + l15;
            float v0 = fmaxf(acc[mi][ni][0] + bias.x, 0.f);
            float v1 = fmaxf(acc[mi][ni][1] + bias.y, 0.f);
            float v2 = fmaxf(acc[mi][ni][2] + bias.z, 0.f);
            float v3 = fmaxf(acc[mi][ni][3] + bias.w, 0.f);
            uint2 pk;
            pk.x = (unsigned)f2bf(v0) | ((unsigned)f2bf(v1) << 16);
            pk.y = (unsigned)f2bf(v2) | ((unsigned)f2bf(v3) << 16);
            *(uint2*)&hT[((size_t)b * T_ + t) * C2 + obase + mi * 16 + q * 4] = pk;
        }
    }
}

// ---- K5: per-channel partial stats of hT (column sums; o is fast axis)
__global__ __launch_bounds__(256) void k_stats2h(const unsigned short* __restrict__ hT,
        float* __restrict__ p2s, float* __restrict__ p2q) {
    int tid = threadIdx.x;
    size_t r0 = (size_t)blockIdx.x * 128;
    float s = 0.f, sq = 0.f;
    for (int r = 0; r < 128; ++r) {
        float v = bf2f(hT[(r0 + r) * C2 + tid]);
        s += v; sq += v * v;
    }
    p2s[blockIdx.x * C2 + tid] = s;
    p2q[blockIdx.x * C2 + tid] = sq;
}

// ---- K6: reduce partials -> scale2/shift2 (1 block x 256)
__global__ void k_scales2(const float* __restrict__ p2s, const float* __restrict__ p2q,
        const float* __restrict__ g, const float* __restrict__ bb,
        float* __restrict__ scale, float* __restrict__ shift) {
    int c = threadIdx.x;
    float s = 0.f, sq = 0.f;
    for (int i = 0; i < 512; ++i) { s += p2s[i * C2 + c]; sq += p2q[i * C2 + c]; }
    float n = (float)(B_ * T_);
    float mean = s / n;
    float var  = sq / n - mean * mean;
    float sc   = g[c] * rsqrtf(var + EPSF);
    scale[c] = sc;
    shift[c] = bb[c] - mean * sc;
}

// ---- K7: fold BN2 into w2 -> w2e bf16, b2e
__global__ void k_fold2(const float* __restrict__ w2, const float* __restrict__ b2,
                        const float* __restrict__ scale2, const float* __restrict__ shift2,
                        unsigned short* __restrict__ w2e, float* __restrict__ b2e) {
    int o = blockIdx.x, tid = threadIdx.x;   // tid == c2
    float w = w2[(size_t)o * C2 + tid];
    float p = w * shift2[tid];
    w2e[(size_t)o * C2 + tid] = f2bf(w * scale2[tid]);
    __shared__ float rs[256];
    rs[tid] = p; __syncthreads();
    for (int off = 128; off > 0; off >>= 1) {
        if (tid < off) rs[tid] += rs[tid + off];
        __syncthreads();
    }
    if (tid == 0) b2e[o] = b2[o] + rs[0];
}

// ---- K8: GEMM2: out = w2e @ hT + b2e, split mu/logvar. 64(o) x 128(t), BK=32.
__global__ __launch_bounds__(256) void k_gemm2(const unsigned short* __restrict__ hT,
        const unsigned short* __restrict__ w2e, const float* __restrict__ b2e,
        float* __restrict__ out) {
    __shared__ unsigned short sA[64 * 32];
    __shared__ unsigned short sB[128 * 32];
    int bn = blockIdx.x, b = blockIdx.y;
    int tid = threadIdx.x;
    int wave = tid >> 6, lane = tid & 63;
    int l15 = lane & 15, q = lane >> 4;
    f32x4 acc[4][2] = {};
    const unsigned short* hblk = hT + ((size_t)b * T_ + (size_t)bn * 128) * C2;

    for (int k0 = 0; k0 < C2; k0 += 32) {
        {
            int row = tid >> 2, cq = tid & 3;
            *(uint4*)&sA[row * 32 + cq * 8] = *(const uint4*)(w2e + (size_t)row * C2 + k0 + cq * 8);
        }
        #pragma unroll
        for (int i = 0; i < 2; ++i) {
            int task = tid + i * 256;
            int row = task >> 2, cq = task & 3;
            *(uint4*)&sB[row * 32 + cq * 8] = *(const uint4*)(hblk + (size_t)row * C2 + k0 + cq * 8);
        }
        __syncthreads();
        bf16x8 af[4], bfr[2];
        #pragma unroll
        for (int mi = 0; mi < 4; ++mi)
            af[mi] = *((const bf16x8*)&sA[(mi * 16 + l15) * 32 + q * 8]);
        #pragma unroll
        for (int ni = 0; ni < 2; ++ni)
            bfr[ni] = *((const bf16x8*)&sB[(wave * 32 + ni * 16 + l15) * 32 + q * 8]);
        #pragma unroll
        for (int mi = 0; mi < 4; ++mi)
            #pragma unroll
            for (int ni = 0; ni < 2; ++ni)
                acc[mi][ni] = __builtin_amdgcn_mfma_f32_16x16x32_bf16(af[mi], bfr[ni], acc[mi][ni], 0, 0, 0);
        __syncthreads();
    }
    int tbase = bn * 128 + wave * 32;
    #pragma unroll
    for (int mi = 0; mi < 4; ++mi) {
        #pragma unroll
        for (int reg = 0; reg < 4; ++reg) {
            int o = mi * 16 + q * 4 + reg;
            float bias = b2e[o];
            size_t base = (o < 32)
                ? ((size_t)b * 32 * T_ + (size_t)o * T_)
                : (2097152u + (size_t)b * 32 * T_ + (size_t)(o - 32) * T_);
            #pragma unroll
            for (int ni = 0; ni < 2; ++ni) {
                int t = tbase + ni * 16 + l15;
                out[base + t] = acc[mi][ni][reg] + bias;
            }
        }
    }
}

extern "C" void kernel_launch(void* const* d_in, const int* in_sizes, int n_in,
                              void* d_out, int out_size, void* d_ws, size_t ws_size,
                              hipStream_t stream) {
    const float* x   = (const float*)d_in[0];
    const float* g1  = (const float*)d_in[1];
    const float* bb1 = (const float*)d_in[2];
    const float* w1  = (const float*)d_in[3];
    const float* b1  = (const float*)d_in[4];
    const float* g2  = (const float*)d_in[5];
    const float* bb2 = (const float*)d_in[6];
    const float* w2  = (const float*)d_in[7];
    const float* b2  = (const float*)d_in[8];
    float* out = (float*)d_out;

    char* ws = (char*)d_ws;
    float* scale1 = (float*)(ws + 0);
    float* shift1 = (float*)(ws + 4096);
    float* b1e    = (float*)(ws + 8192);
    float* scale2 = (float*)(ws + 12288);
    float* shift2 = (float*)(ws + 16384);
    float* b2e    = (float*)(ws + 20480);
    float* psum   = (float*)(ws + 24576);                 // [32][1024]  128 KiB
    float* psq    = (float*)(ws + 155648);                // [32][1024]  128 KiB
    float* p2s    = (float*)(ws + 286720);                // [512][256]  512 KiB
    float* p2q    = (float*)(ws + 811008);                // [512][256]  512 KiB
    unsigned short* w1e = (unsigned short*)(ws + 1335296);    // 512 KiB
    unsigned short* w2e = (unsigned short*)(ws + 1859584);    // 32 KiB
    unsigned short* xT  = (unsigned short*)(ws + 1892352);    // 128 MiB
    unsigned short* hT  = (unsigned short*)(ws + 1892352 + 134217728); // 32 MiB

    k_prep   <<<dim3(16, 32), dim3(256), 0, stream>>>(x, xT, psum, psq);
    k_scales1<<<dim3(4),      dim3(256), 0, stream>>>(psum, psq, g1, bb1, scale1, shift1);
    k_fold1  <<<dim3(256),    dim3(256), 0, stream>>>(w1, b1, scale1, shift1, w1e, b1e);
    k_gemm1  <<<dim3(2, 16, 32), dim3(256), 0, stream>>>(xT, w1e, b1e, hT);
    k_stats2h<<<dim3(512),    dim3(256), 0, stream>>>(hT, p2s, p2q);
    k_scales2<<<dim3(1),      dim3(256), 0, stream>>>(p2s, p2q, g2, bb2, scale2, shift2);
    k_fold2  <<<dim3(64),     dim3(256), 0, stream>>>(w2, b2, scale2, shift2, w2e, b2e);
    k_gemm2  <<<dim3(16, 32), dim3(256), 0, stream>>>(hT, w2e, b2e, out);
}

// Round 3
// 536.178 us; speedup vs baseline: 1.0051x; 1.0037x over previous
//
#include <hip/hip_runtime.h>

#define B_  32
#define C1  1024
#define C2  256
#define T_  2048
#define EPSF 1e-5f
#define CPAD 72   // prep LDS row pitch in halfwords (144 B: 16-B aligned rows)

typedef __attribute__((ext_vector_type(8))) short bf16x8;
typedef __attribute__((ext_vector_type(4))) float f32x4;

static __device__ __forceinline__ unsigned short f2bf(float f) {
    union { float f; unsigned u; } v; v.f = f;
    unsigned r = v.u + 0x7fffu + ((v.u >> 16) & 1u);   // RNE
    return (unsigned short)(r >> 16);
}
// async global->LDS, 16 B per lane; lds dest = wave-uniform base + lane*16
static __device__ __forceinline__ void g2l16(const void* g, void* l) {
    __builtin_amdgcn_global_load_lds(
        (const __attribute__((address_space(1))) unsigned int*)g,
        (__attribute__((address_space(3))) unsigned int*)l, 16, 0, 0);
}

// ---- K1: fused transpose+convert+partial stats: x[b][c][t] -> xT[b][t][c] bf16
__global__ __launch_bounds__(256) void k_prep(const float* __restrict__ x,
        unsigned short* __restrict__ xT, float* __restrict__ psum, float* __restrict__ psq) {
    __shared__ unsigned short tile[64 * CPAD];
    __shared__ float red[256];
    int ct = blockIdx.x, b = blockIdx.y, tid = threadIdx.x;
    int c0 = ct * 64;
    int cl = tid >> 2, t4 = tid & 3;
    const float* xrow = x + (size_t)b * C1 * T_ + (size_t)(c0 + cl) * T_;
    float s = 0.f, sq = 0.f;
    for (int t0 = 0; t0 < T_; t0 += 64) {
        #pragma unroll
        for (int j = 0; j < 4; ++j) {
            int tl = j * 16 + t4 * 4;
            float4 v = *(const float4*)(xrow + t0 + tl);
            s  += v.x + v.y + v.z + v.w;
            sq += v.x * v.x + v.y * v.y + v.z * v.z + v.w * v.w;
            tile[(tl + 0) * CPAD + cl] = f2bf(v.x);
            tile[(tl + 1) * CPAD + cl] = f2bf(v.y);
            tile[(tl + 2) * CPAD + cl] = f2bf(v.z);
            tile[(tl + 3) * CPAD + cl] = f2bf(v.w);
        }
        __syncthreads();
        #pragma unroll
        for (int j = 0; j < 2; ++j) {
            int w = tid + j * 256;
            int tl = w >> 3, cu = w & 7;
            uint4 vv = *(const uint4*)&tile[tl * CPAD + cu * 8];
            *(uint4*)&xT[((size_t)b * T_ + t0 + tl) * C1 + c0 + cu * 8] = vv;
        }
        __syncthreads();
    }
    red[tid] = s; __syncthreads();
    if (tid < 64)
        psum[(size_t)b * C1 + c0 + tid] = red[4*tid] + red[4*tid+1] + red[4*tid+2] + red[4*tid+3];
    __syncthreads();
    red[tid] = sq; __syncthreads();
    if (tid < 64)
        psq[(size_t)b * C1 + c0 + tid]  = red[4*tid] + red[4*tid+1] + red[4*tid+2] + red[4*tid+3];
}

// ---- K2: fused scales1+fold1: per-o block; each thread owns 4 channels
__global__ __launch_bounds__(256) void k_fold1(const float* __restrict__ w1,
        const float* __restrict__ b1, const float* __restrict__ g1, const float* __restrict__ bb1,
        const float* __restrict__ psum, const float* __restrict__ psq,
        unsigned short* __restrict__ w1e, float* __restrict__ b1e) {
    int o = blockIdx.x, tid = threadIdx.x;
    int c = tid * 4;
    float4 s = {0,0,0,0}, sq = {0,0,0,0};
    for (int b = 0; b < B_; ++b) {
        float4 a = *(const float4*)(psum + (size_t)b * C1 + c);
        float4 q = *(const float4*)(psq  + (size_t)b * C1 + c);
        s.x += a.x; s.y += a.y; s.z += a.z; s.w += a.w;
        sq.x += q.x; sq.y += q.y; sq.z += q.z; sq.w += q.w;
    }
    const float n = (float)(B_ * T_);
    float4 gg = *(const float4*)(g1 + c);
    float4 bv = *(const float4*)(bb1 + c);
    float m0 = s.x / n, m1 = s.y / n, m2 = s.z / n, m3 = s.w / n;
    float sc0 = gg.x * rsqrtf(sq.x / n - m0 * m0 + EPSF);
    float sc1 = gg.y * rsqrtf(sq.y / n - m1 * m1 + EPSF);
    float sc2 = gg.z * rsqrtf(sq.z / n - m2 * m2 + EPSF);
    float sc3 = gg.w * rsqrtf(sq.w / n - m3 * m3 + EPSF);
    float sh0 = bv.x - m0 * sc0, sh1 = bv.y - m1 * sc1;
    float sh2 = bv.z - m2 * sc2, sh3 = bv.w - m3 * sc3;
    float4 w = ((const float4*)(w1 + (size_t)o * C1))[tid];
    float p = w.x * sh0 + w.y * sh1 + w.z * sh2 + w.w * sh3;
    uint2 pk;
    pk.x = (unsigned)f2bf(w.x * sc0) | ((unsigned)f2bf(w.y * sc1) << 16);
    pk.y = (unsigned)f2bf(w.z * sc2) | ((unsigned)f2bf(w.w * sc3) << 16);
    *((uint2*)(w1e + (size_t)o * C1 + c)) = pk;
    __shared__ float rs[256];
    rs[tid] = p; __syncthreads();
    for (int off = 128; off > 0; off >>= 1) {
        if (tid < off) rs[tid] += rs[tid + off];
        __syncthreads();
    }
    if (tid == 0) b1e[o] = b1[o] + rs[0];
}

// ---- K3: GEMM1 256(o)x128(t), K=1024, BK=32. xT read ONCE per element.
// Epilogue: bias+relu -> hT bf16, plus per-block h-stats partials.
__global__ __launch_bounds__(256, 2) void k_gemm1(const unsigned short* __restrict__ xT,
        const unsigned short* __restrict__ w1e, const float* __restrict__ b1e,
        unsigned short* __restrict__ hT, float* __restrict__ p2s, float* __restrict__ p2q) {
    __shared__ unsigned short sA[256 * 32];   // 16 KiB  w1e tile [o][k]
    __shared__ unsigned short sB[128 * 32];   //  8 KiB  xT tile [t][k]
    int bn = blockIdx.x, b = blockIdx.y;
    int tid = threadIdx.x;
    int wave = tid >> 6, lane = tid & 63;
    int wm = wave >> 1, wn = wave & 1;        // wave: 128(o) x 64(t)
    int l15 = lane & 15, q = lane >> 4;
    f32x4 acc[8][4] = {};
    const unsigned short* xblk = xT + ((size_t)b * T_ + (size_t)bn * 128) * C1;

    for (int k0 = 0; k0 < C1; k0 += 32) {
        #pragma unroll
        for (int i = 0; i < 4; ++i) {         // A: 16 segments of 1 KiB
            int idx = (wave * 4 + i) * 64 + lane;
            int row = idx >> 2, cq = idx & 3;
            g2l16(w1e + (size_t)row * C1 + k0 + cq * 8, &sA[(wave * 4 + i) * 512]);
        }
        #pragma unroll
        for (int i = 0; i < 2; ++i) {         // B: 8 segments
            int idx = (wave * 2 + i) * 64 + lane;
            int row = idx >> 2, cq = idx & 3;
            g2l16(xblk + (size_t)row * C1 + k0 + cq * 8, &sB[(wave * 2 + i) * 512]);
        }
        __syncthreads();
        bf16x8 bfr[4];
        #pragma unroll
        for (int ni = 0; ni < 4; ++ni)
            bfr[ni] = *((const bf16x8*)&sB[(wn * 64 + ni * 16 + l15) * 32 + q * 8]);
        #pragma unroll
        for (int mi = 0; mi < 8; ++mi) {
            bf16x8 af = *((const bf16x8*)&sA[(wm * 128 + mi * 16 + l15) * 32 + q * 8]);
            #pragma unroll
            for (int ni = 0; ni < 4; ++ni)
                acc[mi][ni] = __builtin_amdgcn_mfma_f32_16x16x32_bf16(af, bfr[ni], acc[mi][ni], 0, 0, 0);
        }
        __syncthreads();
    }
    // epilogue. C/D: col(t)=l15, row(o)=q*4+reg
    int obase = wm * 128;
    int tbase = bn * 128 + wn * 64;
    int prow = (b * 16 + bn) * 2 + wn;        // 1024 partial rows
    #pragma unroll
    for (int mi = 0; mi < 8; ++mi) {
        int og = obase + mi * 16 + q * 4;
        float4 bias = *(const float4*)&b1e[og];
        float s0 = 0, s1 = 0, s2 = 0, s3 = 0, q0 = 0, q1 = 0, q2 = 0, q3 = 0;
        #pragma unroll
        for (int ni = 0; ni < 4; ++ni) {
            int t = tbase + ni * 16 + l15;
            float v0 = fmaxf(acc[mi][ni][0] + bias.x, 0.f);
            float v1 = fmaxf(acc[mi][ni][1] + bias.y, 0.f);
            float v2 = fmaxf(acc[mi][ni][2] + bias.z, 0.f);
            float v3 = fmaxf(acc[mi][ni][3] + bias.w, 0.f);
            s0 += v0; q0 += v0 * v0;  s1 += v1; q1 += v1 * v1;
            s2 += v2; q2 += v2 * v2;  s3 += v3; q3 += v3 * v3;
            uint2 pk;
            pk.x = (unsigned)f2bf(v0) | ((unsigned)f2bf(v1) << 16);
            pk.y = (unsigned)f2bf(v2) | ((unsigned)f2bf(v3) << 16);
            *(uint2*)&hT[((size_t)b * T_ + t) * C2 + og] = pk;
        }
        #pragma unroll
        for (int m = 1; m <= 8; m <<= 1) {    // butterfly over l15 (16-lane groups)
            s0 += __shfl_xor(s0, m); s1 += __shfl_xor(s1, m);
            s2 += __shfl_xor(s2, m); s3 += __shfl_xor(s3, m);
            q0 += __shfl_xor(q0, m); q1 += __shfl_xor(q1, m);
            q2 += __shfl_xor(q2, m); q3 += __shfl_xor(q3, m);
        }
        if (l15 == 0) {
            *(float4*)&p2s[(size_t)prow * C2 + og] = make_float4(s0, s1, s2, s3);
            *(float4*)&p2q[(size_t)prow * C2 + og] = make_float4(q0, q1, q2, q3);
        }
    }
}

// ---- K4: fused scales2+fold2: 64 blocks (one per o); thread = channel c
__global__ __launch_bounds__(256) void k_fold2(const float* __restrict__ w2,
        const float* __restrict__ b2, const float* __restrict__ g2, const float* __restrict__ bb2,
        const float* __restrict__ p2s, const float* __restrict__ p2q,
        unsigned short* __restrict__ w2e, float* __restrict__ b2e) {
    int o = blockIdx.x, tid = threadIdx.x;   // tid == c
    float s = 0.f, sq = 0.f;
    for (int r = 0; r < 1024; ++r) {
        s  += p2s[(size_t)r * C2 + tid];
        sq += p2q[(size_t)r * C2 + tid];
    }
    const float n = (float)(B_ * T_);
    float mean = s / n;
    float sc = g2[tid] * rsqrtf(sq / n - mean * mean + EPSF);
    float sh = bb2[tid] - mean * sc;
    float w = w2[(size_t)o * C2 + tid];
    float p = w * sh;
    w2e[(size_t)o * C2 + tid] = f2bf(w * sc);
    __shared__ float rs[256];
    rs[tid] = p; __syncthreads();
    for (int off = 128; off > 0; off >>= 1) {
        if (tid < off) rs[tid] += rs[tid + off];
        __syncthreads();
    }
    if (tid == 0) b2e[o] = b2[o] + rs[0];
}

// ---- K5: GEMM2: out = w2e @ hT + b2e, split mu/logvar. 64(o) x 128(t), K=256.
__global__ __launch_bounds__(256) void k_gemm2(const unsigned short* __restrict__ hT,
        const unsigned short* __restrict__ w2e, const float* __restrict__ b2e,
        float* __restrict__ out) {
    __shared__ unsigned short sA[64 * 32];    // 4 KiB
    __shared__ unsigned short sB[128 * 32];   // 8 KiB
    int bn = blockIdx.x, b = blockIdx.y;
    int tid = threadIdx.x;
    int wave = tid >> 6, lane = tid & 63;
    int l15 = lane & 15, q = lane >> 4;
    f32x4 acc[4][2] = {};
    const unsigned short* hblk = hT + ((size_t)b * T_ + (size_t)bn * 128) * C2;

    for (int k0 = 0; k0 < C2; k0 += 32) {
        {                                      // A: 4 segments, one per wave
            int idx = wave * 64 + lane;
            int row = idx >> 2, cq = idx & 3;
            g2l16(w2e + (size_t)row * C2 + k0 + cq * 8, &sA[wave * 512]);
        }
        #pragma unroll
        for (int i = 0; i < 2; ++i) {          // B: 8 segments
            int idx = (wave * 2 + i) * 64 + lane;
            int row = idx >> 2, cq = idx & 3;
            g2l16(hblk + (size_t)row * C2 + k0 + cq * 8, &sB[(wave * 2 + i) * 512]);
        }
        __syncthreads();
        bf16x8 af[4], bfr[2];
        #pragma unroll
        for (int mi = 0; mi < 4; ++mi)
            af[mi] = *((const bf16x8*)&sA[(mi * 16 + l15) * 32 + q * 8]);
        #pragma unroll
        for (int ni = 0; ni < 2; ++ni)
            bfr[ni] = *((const bf16x8*)&sB[(wave * 32 + ni * 16 + l15) * 32 + q * 8]);
        #pragma unroll
        for (int mi = 0; mi < 4; ++mi)
            #pragma unroll
            for (int ni = 0; ni < 2; ++ni)
                acc[mi][ni] = __builtin_amdgcn_mfma_f32_16x16x32_bf16(af[mi], bfr[ni], acc[mi][ni], 0, 0, 0);
        __syncthreads();
    }
    int tbase = bn * 128 + wave * 32;
    #pragma unroll
    for (int mi = 0; mi < 4; ++mi) {
        #pragma unroll
        for (int reg = 0; reg < 4; ++reg) {
            int o = mi * 16 + q * 4 + reg;
            float bias = b2e[o];
            size_t base = (o < 32)
                ? ((size_t)b * 32 * T_ + (size_t)o * T_)
                : (2097152u + (size_t)b * 32 * T_ + (size_t)(o - 32) * T_);
            #pragma unroll
            for (int ni = 0; ni < 2; ++ni) {
                int t = tbase + ni * 16 + l15;
                out[base + t] = acc[mi][ni][reg] + bias;
            }
        }
    }
}

extern "C" void kernel_launch(void* const* d_in, const int* in_sizes, int n_in,
                              void* d_out, int out_size, void* d_ws, size_t ws_size,
                              hipStream_t stream) {
    const float* x   = (const float*)d_in[0];
    const float* g1  = (const float*)d_in[1];
    const float* bb1 = (const float*)d_in[2];
    const float* w1  = (const float*)d_in[3];
    const float* b1  = (const float*)d_in[4];
    const float* g2  = (const float*)d_in[5];
    const float* bb2 = (const float*)d_in[6];
    const float* w2  = (const float*)d_in[7];
    const float* b2  = (const float*)d_in[8];
    float* out = (float*)d_out;

    char* ws = (char*)d_ws;
    float* b1e  = (float*)(ws + 0);                       //   4 KiB
    float* b2e  = (float*)(ws + 4096);                    //   1 KiB
    float* psum = (float*)(ws + 8192);                    // 128 KiB  [32][1024]
    float* psq  = (float*)(ws + 139264);                  // 128 KiB
    float* p2s  = (float*)(ws + 270336);                  //   1 MiB  [1024][256]
    float* p2q  = (float*)(ws + 1318912);                 //   1 MiB
    unsigned short* w1e = (unsigned short*)(ws + 2367488);    // 512 KiB
    unsigned short* w2e = (unsigned short*)(ws + 2891776);    //  32 KiB
    unsigned short* xT  = (unsigned short*)(ws + 2924544);    // 128 MiB [b][t][c1]
    unsigned short* hT  = (unsigned short*)(ws + 2924544 + 134217728); // 32 MiB [b][t][c2]

    k_prep <<<dim3(16, 32), dim3(256), 0, stream>>>(x, xT, psum, psq);
    k_fold1<<<dim3(256),    dim3(256), 0, stream>>>(w1, b1, g1, bb1, psum, psq, w1e, b1e);
    k_gemm1<<<dim3(16, 32), dim3(256), 0, stream>>>(xT, w1e, b1e, hT, p2s, p2q);
    k_fold2<<<dim3(64),     dim3(256), 0, stream>>>(w2, b2, g2, bb2, p2s, p2q, w2e, b2e);
    k_gemm2<<<dim3(16, 32), dim3(256), 0, stream>>>(hT, w2e, b2e, out);
}